// Round 8
// baseline (1039.585 us; speedup 1.0000x reference)
//
#include <hip/hip_runtime.h>
#include <math.h>

// Problem constants
#define DD   16     // model dim
#define NH   8      // heads (head dim = 2)
#define NL   8      // layers
#define FFD  16     // ff dim
#define KK   35     // conv kernel / patch size
#define SEQ  3500   // input seq
#define NP   100    // patches
#define SS   101    // tokens (cls + patches)
#define NT   256    // 4 waves; 1 batch/block; grid = 2048 -> up to 8 blocks/CU
#define TSPLIT 51   // key split: waves 0,1 -> t in [0,51); waves 2,3 -> [51,101)
#define ROWDW 21    // kv row stride in dwords (84 B, odd -> <=2-way write conflicts)
#define PARTSTR 13  // partial row stride in dwords (odd -> conflict-free)
#define KVDW  (SS * ROWDW)        // 2121 dw
#define PARTDW (2 * SS * PARTSTR) // 2626 dw
#define UNIDW 2626                // union(kv, partial) region (10.5 KB)
#define NWPAIR 6144               // packed weight half2 count (24.6 KB in d_ws)

typedef __fp16 h2 __attribute__((ext_vector_type(2)));

__device__ __forceinline__ float fdot2(h2 a, h2 b, float c) {
#if __has_builtin(__builtin_amdgcn_fdot2)
  return __builtin_amdgcn_fdot2(a, b, c, false);
#else
  return c + (float)a.x * (float)b.x + (float)a.y * (float)b.y;
#endif
}
__device__ __forceinline__ float exp2_fast(float x) {
#if __has_builtin(__builtin_amdgcn_exp2f)
  return __builtin_amdgcn_exp2f(x);
#else
  return exp2f(x);
#endif
}
__device__ __forceinline__ float rcp_fast(float x) {
#if __has_builtin(__builtin_amdgcn_rcpf)
  return __builtin_amdgcn_rcpf(x);
#else
  return 1.0f / x;
#endif
}
__device__ __forceinline__ h2 pk_h2(float a, float b) {
#if __has_builtin(__builtin_amdgcn_cvt_pkrtz)
  return __builtin_amdgcn_cvt_pkrtz(a, b);
#else
  h2 r; r.x = (__fp16)a; r.y = (__fp16)b; return r;
#endif
}
__device__ __forceinline__ unsigned pk_u(float a, float b) {
  return __builtin_bit_cast(unsigned, pk_h2(a, b));
}
__device__ __forceinline__ h2 as_h2(unsigned u) {
  return __builtin_bit_cast(h2, u);
}

__device__ __forceinline__ void lnorm16(float* h, const float* __restrict__ g,
                                        const float* __restrict__ bb) {
  float mu = 0.f;
  #pragma unroll
  for (int d = 0; d < DD; ++d) mu += h[d];
  mu *= (1.f / DD);
  float var = 0.f;
  #pragma unroll
  for (int d = 0; d < DD; ++d) { float c = h[d] - mu; var += c * c; }
  var *= (1.f / DD);
  const float r = rsqrtf(var + 1e-5f);
  #pragma unroll
  for (int d = 0; d < DD; ++d) h[d] = (h[d] - mu) * r * g[d] + bb[d];
}

// 16-dim dot via 8 x v_dot2_f32_f16 (weights pre-packed as half2)
__device__ __forceinline__ float dot16(const h2* hv, const unsigned* __restrict__ w, float acc) {
  #pragma unroll
  for (int i = 0; i < 8; ++i) acc = fdot2(hv[i], as_h2(w[i]), acc);
  return acc;
}

// ---- prep: pack [Wqkv|Wo|W1|W2] f32 pairs into half2 ----
__global__ __launch_bounds__(256)
void pack_weights(const float* __restrict__ Wqkv, const float* __restrict__ Wo,
                  const float* __restrict__ W1,   const float* __restrict__ W2,
                  unsigned* __restrict__ dst)
{
  const int i = blockIdx.x * 256 + threadIdx.x;
  if (i >= NWPAIR) return;
  float a, b;
  if (i < 3072)      { a = Wqkv[2*i];        b = Wqkv[2*i+1]; }
  else if (i < 4096) { int j = i - 3072; a = Wo[2*j]; b = Wo[2*j+1]; }
  else if (i < 5120) { int j = i - 4096; a = W1[2*j]; b = W1[2*j+1]; }
  else               { int j = i - 5120; a = W2[2*j]; b = W2[2*j+1]; }
  dst[i] = pk_u(a, b);
}

// -------- primary: key-split across wave pairs; VGPR-friendly (no forced cap) ----
__global__ __launch_bounds__(NT, 4)
void transformer_fwd_t(const float* __restrict__ x,
                       const float* __restrict__ conv_w,  const float* __restrict__ conv_b,
                       const float* __restrict__ cls_emb,
                       const float* __restrict__ bqkv,
                       const float* __restrict__ bo,
                       const float* __restrict__ b1,
                       const float* __restrict__ b2,
                       const float* __restrict__ ln1_g,   const float* __restrict__ ln1_b,
                       const float* __restrict__ ln2_g,   const float* __restrict__ ln2_b,
                       const float* __restrict__ lnf_g,   const float* __restrict__ lnf_b,
                       const float* __restrict__ end_w,   const float* __restrict__ end_b,
                       const float* __restrict__ head_w,  const float* __restrict__ head_b,
                       float* __restrict__ out,
                       const unsigned* __restrict__ wpk)
{
  // union region: kv rows (2121 dw, live proj->t-loop) / fp16 partials (2626 dw,
  // live after t-loop). Disjoint live ranges separated by barriers.
  __shared__ __align__(16) unsigned s_uni[UNIDW];
  __shared__ float s_cls[DD];
  __shared__ float s_lat[NP];

  const int tid   = threadIdx.x;
  const int wid   = tid >> 6;
  const int lane  = tid & 63;
  const int qhalf = wid & 1;           // query rows: 0..63 / 64..127
  const int khalf = wid >> 1;          // key range:  [0,51) / [51,101)
  const int r     = (qhalf << 6) + lane;
  const bool act  = (r < SS);
  const int tA    = khalf ? TSPLIT : 0;
  const int tB    = khalf ? SS : TSPLIT;
  const size_t b  = blockIdx.x;

  // ---- conv patch embed (khalf pair redundant by design) ----
  float h[DD];
  if (act) {
    if (r == 0) {
      #pragma unroll
      for (int d = 0; d < DD; ++d) h[d] = cls_emb[d];
    } else {
      const float* xp = x + b * SEQ + (r - 1) * KK;
      float xv[KK];
      #pragma unroll
      for (int k = 0; k < KK; ++k) xv[k] = xp[k];
      #pragma unroll
      for (int f = 0; f < DD; ++f) {
        float acc = conv_b[f];
        #pragma unroll
        for (int k = 0; k < KK; ++k) acc += xv[k] * conv_w[f * KK + k];
        h[f] = acc;
      }
    }
  }

  const float qs = 1.4426950408889634f * 0.70710678118654752f; // log2e / sqrt(2)

  for (int l = 0; l < NL; ++l) {
    const unsigned* wq16 = wpk + l * 384;
    const unsigned* wo16 = wpk + 3072 + l * 128;
    const unsigned* w116 = wpk + 4096 + l * 128;
    const unsigned* w216 = wpk + 5120 + l * 128;
    const float* bq  = bqkv + l * (3 * DD);
    const float* bol = bo   + l * DD;
    const float* b1l = b1   + l * FFD;
    const float* b2l = b2   + l * DD;
    const float* g1  = ln1_g + l * DD;  const float* be1 = ln1_b + l * DD;
    const float* g2  = ln2_g + l * DD;  const float* be2 = ln2_b + l * DD;

    __syncthreads();   // (1) prev layer's partial reads complete before kv clobbers

    h2 q2[NH];
    if (act) {
      h2 hv[8];
      #pragma unroll
      for (int i = 0; i < 8; ++i) hv[i] = pk_h2(h[2*i], h[2*i+1]);

      #pragma unroll
      for (int hh = 0; hh < NH; ++hh) {
        const float a0 = dot16(hv, &wq16[(2*hh    ) * 8], bq[2*hh]);
        const float a1 = dot16(hv, &wq16[(2*hh + 1) * 8], bq[2*hh+1]);
        q2[hh] = pk_h2(a0 * qs, a1 * qs);
      }
      if (khalf == 0) {
        unsigned row[16];
        #pragma unroll
        for (int e = 0; e < 16; e += 2) {  // k
          const float a0 = dot16(hv, &wq16[(DD + e    ) * 8], bq[DD + e]);
          const float a1 = dot16(hv, &wq16[(DD + e + 1) * 8], bq[DD + e + 1]);
          row[e >> 1] = pk_u(a0, a1);
        }
        #pragma unroll
        for (int e = 0; e < 16; e += 2) {  // v
          const float a0 = dot16(hv, &wq16[(2*DD + e    ) * 8], bq[2*DD + e]);
          const float a1 = dot16(hv, &wq16[(2*DD + e + 1) * 8], bq[2*DD + e + 1]);
          row[8 + (e >> 1)] = pk_u(a0, a1);
        }
        unsigned* dst = &s_uni[r * ROWDW];
        uint4* d4 = (uint4*)dst;
        d4[0] = make_uint4(row[0],  row[1],  row[2],  row[3]);
        d4[1] = make_uint4(row[4],  row[5],  row[6],  row[7]);
        d4[2] = make_uint4(row[8],  row[9],  row[10], row[11]);
        d4[3] = make_uint4(row[12], row[13], row[14], row[15]);
      }
    }
    __syncthreads();   // (2) kv visible

    float lsum[NH], cxx[NH], cxy[NH];
    #pragma unroll
    for (int hh = 0; hh < NH; ++hh) { lsum[hh] = 0.f; cxx[hh] = 0.f; cxy[hh] = 0.f; }

    if (act) {
      #pragma unroll 2
      for (int t = tA; t < tB; ++t) {
        const uint4* kt = (const uint4*)&s_uni[t * ROWDW];
        const uint4 a0 = kt[0], a1 = kt[1], a2 = kt[2], a3 = kt[3];
        const unsigned ku[8] = {a0.x, a0.y, a0.z, a0.w, a1.x, a1.y, a1.z, a1.w};
        const unsigned vu[8] = {a2.x, a2.y, a2.z, a2.w, a3.x, a3.y, a3.z, a3.w};
        #pragma unroll
        for (int hh = 0; hh < NH; ++hh) {
          const h2 kk = as_h2(ku[hh]);
          const h2 vv = as_h2(vu[hh]);
          const float p = exp2_fast(fdot2(q2[hh], kk, 0.0f));
          lsum[hh] += p;
          cxx[hh]  += (float)vv.x * p;   // v_fma_mix
          cxy[hh]  += (float)vv.y * p;
        }
      }
    }
    __syncthreads();   // (3) all kv reads done before partials clobber the union

    if (act) {
      unsigned* pp = &s_uni[(khalf * SS + r) * PARTSTR];
      #pragma unroll
      for (int i = 0; i < 4; ++i) pp[i]     = pk_u(lsum[2*i], lsum[2*i+1]);
      #pragma unroll
      for (int i = 0; i < 4; ++i) pp[4 + i] = pk_u(cxx[2*i],  cxx[2*i+1]);
      #pragma unroll
      for (int i = 0; i < 4; ++i) pp[8 + i] = pk_u(cxy[2*i],  cxy[2*i+1]);
    }
    __syncthreads();   // (4) partials visible

    if (act) {
      const unsigned* qq = &s_uni[((1 - khalf) * SS + r) * PARTSTR];
      #pragma unroll
      for (int i = 0; i < 4; ++i) {
        const h2 o = as_h2(qq[i]);
        lsum[2*i] += (float)o.x;  lsum[2*i+1] += (float)o.y;
      }
      #pragma unroll
      for (int i = 0; i < 4; ++i) {
        const h2 o = as_h2(qq[4 + i]);
        cxx[2*i] += (float)o.x;  cxx[2*i+1] += (float)o.y;
      }
      #pragma unroll
      for (int i = 0; i < 4; ++i) {
        const h2 o = as_h2(qq[8 + i]);
        cxy[2*i] += (float)o.x;  cxy[2*i+1] += (float)o.y;
      }

      float cx[DD];
      #pragma unroll
      for (int hh = 0; hh < NH; ++hh) {
        const float inv = rcp_fast(lsum[hh]);
        cx[2 * hh]     = cxx[hh] * inv;
        cx[2 * hh + 1] = cxy[hh] * inv;
      }

      // Wo + residual + LN1
      h2 cv[8];
      #pragma unroll
      for (int i = 0; i < 8; ++i) cv[i] = pk_h2(cx[2*i], cx[2*i+1]);
      #pragma unroll
      for (int od = 0; od < DD; ++od)
        h[od] += dot16(cv, &wo16[od * 8], bol[od]);
      lnorm16(h, g1, be1);

      // FF + residual + LN2
      h2 hv2[8];
      #pragma unroll
      for (int i = 0; i < 8; ++i) hv2[i] = pk_h2(h[2*i], h[2*i+1]);
      float fv[FFD];
      #pragma unroll
      for (int f = 0; f < FFD; ++f)
        fv[f] = fmaxf(dot16(hv2, &w116[f * 8], b1l[f]), 0.f);
      h2 fv2[8];
      #pragma unroll
      for (int i = 0; i < 8; ++i) fv2[i] = pk_h2(fv[2*i], fv[2*i+1]);
      #pragma unroll
      for (int od = 0; od < DD; ++od)
        h[od] += dot16(fv2, &w216[od * 8], b2l[od]);
      lnorm16(h, g2, be2);
    }
  }

  // ---- final LN (cls row) + head ----
  __syncthreads();
  if (act && r == 0 && khalf == 0) {
    lnorm16(h, lnf_g, lnf_b);
    #pragma unroll
    for (int d = 0; d < DD; ++d) s_cls[d] = h[d];
  }
  __syncthreads();
  if (tid < NP) {
    float acc = end_b[tid];
    #pragma unroll
    for (int d = 0; d < DD; ++d) acc += s_cls[d] * end_w[tid * DD + d];
    s_lat[tid] = acc * head_w[tid];
  }
  __syncthreads();
  if (tid == 0) {
    float acc = head_b[0];
    for (int o = 0; o < NP; ++o) acc += s_lat[o];
    out[b] = rcp_fast(1.f + exp2_fast(-acc * 1.4426950408889634f));
  }
}

// ---------------- fallback (no ws needed): f32 weights, LDS kv ----------------
#define FB_NBATCH 3
#define FB_NT 320
#define KROW 8
#define VROW 8
#define KREG (SS * KROW + 4)
#define VREG (SS * VROW + 2)
typedef float f2 __attribute__((ext_vector_type(2)));

__global__ __launch_bounds__(FB_NT)
void transformer_fwd_lds(const float* __restrict__ x,
                         const float* __restrict__ conv_w,  const float* __restrict__ conv_b,
                         const float* __restrict__ cls_emb,
                         const float* __restrict__ Wqkv,    const float* __restrict__ bqkv,
                         const float* __restrict__ Wo,      const float* __restrict__ bo,
                         const float* __restrict__ W1,      const float* __restrict__ b1,
                         const float* __restrict__ W2,      const float* __restrict__ b2,
                         const float* __restrict__ ln1_g,   const float* __restrict__ ln1_b,
                         const float* __restrict__ ln2_g,   const float* __restrict__ ln2_b,
                         const float* __restrict__ lnf_g,   const float* __restrict__ lnf_b,
                         const float* __restrict__ end_w,   const float* __restrict__ end_b,
                         const float* __restrict__ head_w,  const float* __restrict__ head_b,
                         float* __restrict__ out, int B)
{
  __shared__ h2    s_K[FB_NBATCH][KREG];
  __shared__ f2    s_V[FB_NBATCH][VREG];
  __shared__ float s_cls[FB_NBATCH][DD];
  __shared__ float s_lat[FB_NBATCH][NP];

  const int tid = threadIdx.x;
  const int j   = tid / SS;
  const int r   = tid - j * SS;
  const int b   = blockIdx.x * FB_NBATCH + j;
  const bool act = (tid < FB_NBATCH * SS) && (b < B);

  float h[DD];
  if (act) {
    if (r == 0) {
      #pragma unroll
      for (int d = 0; d < DD; ++d) h[d] = cls_emb[d];
    } else {
      const float* xp = x + (size_t)b * SEQ + (r - 1) * KK;
      float xv[KK];
      #pragma unroll
      for (int k = 0; k < KK; ++k) xv[k] = xp[k];
      #pragma unroll
      for (int f = 0; f < DD; ++f) {
        float acc = conv_b[f];
        #pragma unroll
        for (int k = 0; k < KK; ++k) acc += xv[k] * conv_w[f * KK + k];
        h[f] = acc;
      }
    }
  }

  const float qs = 1.4426950408889634f * 0.70710678118654752f;

  for (int l = 0; l < NL; ++l) {
    const float* wq  = Wqkv + l * (3 * DD * DD);
    const float* bq  = bqkv + l * (3 * DD);
    const float* wo  = Wo   + l * (DD * DD);
    const float* bol = bo   + l * DD;
    const float* w1  = W1   + l * (FFD * DD);
    const float* b1l = b1   + l * FFD;
    const float* w2  = W2   + l * (DD * FFD);
    const float* b2l = b2   + l * DD;
    const float* g1  = ln1_g + l * DD;  const float* be1 = ln1_b + l * DD;
    const float* g2  = ln2_g + l * DD;  const float* be2 = ln2_b + l * DD;

    __syncthreads();

    h2 q2[NH];
    if (act) {
      #pragma unroll
      for (int hh = 0; hh < NH; ++hh) {
        const int e0 = 2 * hh;
        float a0 = bq[e0], a1 = bq[e0 + 1];
        #pragma unroll
        for (int d = 0; d < DD; ++d) {
          a0 += h[d] * wq[e0 * DD + d];
          a1 += h[d] * wq[(e0 + 1) * DD + d];
        }
        q2[hh] = pk_h2(a0 * qs, a1 * qs);
      }
      h2* kw = &s_K[j][r * KROW];
      #pragma unroll
      for (int hh = 0; hh < NH; ++hh) {
        const int e0 = DD + 2 * hh;
        float a0 = bq[e0], a1 = bq[e0 + 1];
        #pragma unroll
        for (int d = 0; d < DD; ++d) {
          a0 += h[d] * wq[e0 * DD + d];
          a1 += h[d] * wq[(e0 + 1) * DD + d];
        }
        kw[hh] = pk_h2(a0, a1);
      }
      f2* vw = &s_V[j][r * VROW];
      #pragma unroll
      for (int hh = 0; hh < NH; ++hh) {
        const int e0 = 2 * DD + 2 * hh;
        float a0 = bq[e0], a1 = bq[e0 + 1];
        #pragma unroll
        for (int d = 0; d < DD; ++d) {
          a0 += h[d] * wq[e0 * DD + d];
          a1 += h[d] * wq[(e0 + 1) * DD + d];
        }
        f2 vv; vv.x = a0; vv.y = a1;
        vw[hh] = vv;
      }
    }
    __syncthreads();

    if (act) {
      float lsum[NH];
      f2 ctx[NH];
      #pragma unroll
      for (int hh = 0; hh < NH; ++hh) { lsum[hh] = 0.f; ctx[hh].x = 0.f; ctx[hh].y = 0.f; }
      const h2* kp0 = &s_K[j][0];
      const f2* vp0 = &s_V[j][0];
      for (int t = 0; t < SS; ++t) {
        const h2* kp = kp0 + t * KROW;
        const f2* vp = vp0 + t * VROW;
        #pragma unroll
        for (int hh = 0; hh < NH; ++hh) {
          const float p = exp2_fast(fdot2(q2[hh], kp[hh], 0.0f));
          lsum[hh] += p;
          ctx[hh]  += vp[hh] * p;
        }
      }
      float cx[DD];
      #pragma unroll
      for (int hh = 0; hh < NH; ++hh) {
        const float inv = rcp_fast(lsum[hh]);
        cx[2 * hh]     = ctx[hh].x * inv;
        cx[2 * hh + 1] = ctx[hh].y * inv;
      }
      #pragma unroll
      for (int od = 0; od < DD; ++od) {
        float acc = bol[od];
        #pragma unroll
        for (int d = 0; d < DD; ++d) acc += cx[d] * wo[od * DD + d];
        h[od] += acc;
      }
      lnorm16(h, g1, be1);
      float fv[FFD];
      #pragma unroll
      for (int f = 0; f < FFD; ++f) {
        float acc = b1l[f];
        #pragma unroll
        for (int d = 0; d < DD; ++d) acc += h[d] * w1[f * DD + d];
        fv[f] = fmaxf(acc, 0.f);
      }
      #pragma unroll
      for (int od = 0; od < DD; ++od) {
        float acc = b2l[od];
        #pragma unroll
        for (int f = 0; f < FFD; ++f) acc += fv[f] * w2[od * FFD + f];
        h[od] += acc;
      }
      lnorm16(h, g2, be2);
    }
  }

  __syncthreads();
  if (act && r == 0) {
    lnorm16(h, lnf_g, lnf_b);
    #pragma unroll
    for (int d = 0; d < DD; ++d) s_cls[j][d] = h[d];
  }
  __syncthreads();
  if (tid < FB_NBATCH * NP) {
    const int jj = tid / NP;
    const int oo = tid - jj * NP;
    if (blockIdx.x * FB_NBATCH + jj < B) {
      float acc = end_b[oo];
      #pragma unroll
      for (int d = 0; d < DD; ++d) acc += s_cls[jj][d] * end_w[oo * DD + d];
      s_lat[jj][oo] = acc * head_w[oo];
    }
  }
  __syncthreads();
  if (tid < FB_NBATCH) {
    const int bb = blockIdx.x * FB_NBATCH + tid;
    if (bb < B) {
      float acc = head_b[0];
      for (int o = 0; o < NP; ++o) acc += s_lat[tid][o];
      out[bb] = rcp_fast(1.f + exp2_fast(-acc * 1.4426950408889634f));
    }
  }
}

extern "C" void kernel_launch(void* const* d_in, const int* in_sizes, int n_in,
                              void* d_out, int out_size, void* d_ws, size_t ws_size,
                              hipStream_t stream) {
  const float* x       = (const float*)d_in[0];
  const float* conv_w  = (const float*)d_in[1];
  const float* conv_b  = (const float*)d_in[2];
  const float* cls_emb = (const float*)d_in[3];
  const float* Wqkv    = (const float*)d_in[4];
  const float* bqkv    = (const float*)d_in[5];
  const float* Wo      = (const float*)d_in[6];
  const float* bo      = (const float*)d_in[7];
  const float* W1      = (const float*)d_in[8];
  const float* b1      = (const float*)d_in[9];
  const float* W2      = (const float*)d_in[10];
  const float* b2      = (const float*)d_in[11];
  const float* ln1_g   = (const float*)d_in[12];
  const float* ln1_b   = (const float*)d_in[13];
  const float* ln2_g   = (const float*)d_in[14];
  const float* ln2_b   = (const float*)d_in[15];
  const float* lnf_g   = (const float*)d_in[16];
  const float* lnf_b   = (const float*)d_in[17];
  const float* end_w   = (const float*)d_in[18];
  const float* end_b   = (const float*)d_in[19];
  const float* head_w  = (const float*)d_in[20];
  const float* head_b  = (const float*)d_in[21];
  float* out = (float*)d_out;

  const int B = in_sizes[0] / SEQ;   // 2048

  if (ws_size >= NWPAIR * sizeof(unsigned)) {
    unsigned* wpk = (unsigned*)d_ws;
    pack_weights<<<(NWPAIR + 255) / 256, 256, 0, stream>>>(Wqkv, Wo, W1, W2, wpk);
    transformer_fwd_t<<<B, NT, 0, stream>>>(
        x, conv_w, conv_b, cls_emb, bqkv, bo, b1, b2,
        ln1_g, ln1_b, ln2_g, ln2_b, lnf_g, lnf_b, end_w, end_b, head_w, head_b,
        out, wpk);
  } else {
    const int nb = (B + FB_NBATCH - 1) / FB_NBATCH;
    transformer_fwd_lds<<<nb, FB_NT, 0, stream>>>(
        x, conv_w, conv_b, cls_emb, Wqkv, bqkv, Wo, bo, W1, b1, W2, b2,
        ln1_g, ln1_b, ln2_g, ln2_b, lnf_g, lnf_b, end_w, end_b, head_w, head_b,
        out, B);
  }
}

// Round 9
// 483.067 us; speedup vs baseline: 2.1520x; 2.1520x over previous
//
#include <hip/hip_runtime.h>
#include <math.h>

// Problem constants
#define DD   16     // model dim
#define NH   8      // heads (head dim = 2)
#define NL   8      // layers
#define FFD  16     // ff dim
#define KK   35     // conv kernel / patch size
#define SEQ  3500   // input seq
#define NP   100    // patches
#define SS   101    // tokens (cls + patches)
#define NBATCH 2    // batches per block; batch slot = wave>>1 (wave-uniform)
#define NT   256    // 4 waves; grid = 1024 = 4 blocks/CU, 16 waves/CU
// kv row: K 8dw (fp16 pairs) | Vx 8dw (fp32) | Vy 8dw (fp32) | pad 4dw
#define ROWDW 28    // 112 B, 16B-aligned rows -> ds_read_b128 everywhere
#define KVDW (SS * ROWDW)   // 2828 dw per batch slot
#define NWPAIR 6144         // packed weight half2 count (24.6 KB in d_ws)

typedef __fp16 h2 __attribute__((ext_vector_type(2)));
typedef float  f2 __attribute__((ext_vector_type(2)));

__device__ __forceinline__ float fdot2(h2 a, h2 b, float c) {
#if __has_builtin(__builtin_amdgcn_fdot2)
  return __builtin_amdgcn_fdot2(a, b, c, false);
#else
  return c + (float)a.x * (float)b.x + (float)a.y * (float)b.y;
#endif
}
__device__ __forceinline__ float exp2_fast(float x) {
#if __has_builtin(__builtin_amdgcn_exp2f)
  return __builtin_amdgcn_exp2f(x);
#else
  return exp2f(x);
#endif
}
__device__ __forceinline__ float rcp_fast(float x) {
#if __has_builtin(__builtin_amdgcn_rcpf)
  return __builtin_amdgcn_rcpf(x);
#else
  return 1.0f / x;
#endif
}
__device__ __forceinline__ h2 pk_h2(float a, float b) {
#if __has_builtin(__builtin_amdgcn_cvt_pkrtz)
  return __builtin_amdgcn_cvt_pkrtz(a, b);
#else
  h2 r; r.x = (__fp16)a; r.y = (__fp16)b; return r;
#endif
}
__device__ __forceinline__ unsigned pk_u(float a, float b) {
  return __builtin_bit_cast(unsigned, pk_h2(a, b));
}
__device__ __forceinline__ h2 as_h2(unsigned u) {
  return __builtin_bit_cast(h2, u);
}

// VOP3P packed f32 ops (gfx90a+): acc += a * b  /  acc += a
__device__ __forceinline__ void pk_fma(f2& acc, f2 a, f2 b) {
  asm("v_pk_fma_f32 %0, %1, %2, %0" : "+v"(acc) : "v"(a), "v"(b));
}
__device__ __forceinline__ void pk_add(f2& acc, f2 a) {
  asm("v_pk_add_f32 %0, %1, %0" : "+v"(acc) : "v"(a));
}

__device__ __forceinline__ void lnorm16(float* h, const float* __restrict__ g,
                                        const float* __restrict__ bb) {
  float mu = 0.f;
  #pragma unroll
  for (int d = 0; d < DD; ++d) mu += h[d];
  mu *= (1.f / DD);
  float var = 0.f;
  #pragma unroll
  for (int d = 0; d < DD; ++d) { float c = h[d] - mu; var += c * c; }
  var *= (1.f / DD);
  const float r = rsqrtf(var + 1e-5f);
  #pragma unroll
  for (int d = 0; d < DD; ++d) h[d] = (h[d] - mu) * r * g[d] + bb[d];
}

// 16-dim dot via 8 x v_dot2_f32_f16 (weights pre-packed as half2)
__device__ __forceinline__ float dot16(const h2* hv, const unsigned* __restrict__ w, float acc) {
  #pragma unroll
  for (int i = 0; i < 8; ++i) acc = fdot2(hv[i], as_h2(w[i]), acc);
  return acc;
}

// ---- prep: pack [Wqkv|Wo|W1|W2] f32 pairs into half2 ----
__global__ __launch_bounds__(256)
void pack_weights(const float* __restrict__ Wqkv, const float* __restrict__ Wo,
                  const float* __restrict__ W1,   const float* __restrict__ W2,
                  unsigned* __restrict__ dst)
{
  const int i = blockIdx.x * 256 + threadIdx.x;
  if (i >= NWPAIR) return;
  float a, b;
  if (i < 3072)      { a = Wqkv[2*i];        b = Wqkv[2*i+1]; }
  else if (i < 4096) { int j = i - 3072; a = Wo[2*j]; b = Wo[2*j+1]; }
  else if (i < 5120) { int j = i - 4096; a = W1[2*j]; b = W1[2*j+1]; }
  else               { int j = i - 5120; a = W2[2*j]; b = W2[2*j+1]; }
  dst[i] = pk_u(a, b);
}

// -------- primary: R5 structure + packed-f32 t-loop ---------------------------
__global__ __launch_bounds__(NT, 4)
void transformer_fwd_g(const float* __restrict__ x,
                       const float* __restrict__ conv_w,  const float* __restrict__ conv_b,
                       const float* __restrict__ cls_emb,
                       const float* __restrict__ bqkv,
                       const float* __restrict__ bo,
                       const float* __restrict__ b1,
                       const float* __restrict__ b2,
                       const float* __restrict__ ln1_g,   const float* __restrict__ ln1_b,
                       const float* __restrict__ ln2_g,   const float* __restrict__ ln2_b,
                       const float* __restrict__ lnf_g,   const float* __restrict__ lnf_b,
                       const float* __restrict__ end_w,   const float* __restrict__ end_b,
                       const float* __restrict__ head_w,  const float* __restrict__ head_b,
                       float* __restrict__ out,
                       const unsigned* __restrict__ wpk, int B)
{
  __shared__ __align__(16) unsigned s_kv[NBATCH][KVDW];
  __shared__ float s_cls[NBATCH][DD];
  __shared__ float s_lat[NBATCH][NP];

  const int tid  = threadIdx.x;
  const int wid  = tid >> 6;
  const int lane = tid & 63;
  const int j    = wid >> 1;                // wave-uniform batch slot
  const int r    = ((wid & 1) << 6) + lane; // row 0..127
  const int b    = blockIdx.x * NBATCH + j;
  const bool act = (r < SS) && (b < B);

  // ---- conv patch embed ----
  float h[DD];
  if (act) {
    if (r == 0) {
      #pragma unroll
      for (int d = 0; d < DD; ++d) h[d] = cls_emb[d];
    } else {
      const float* xp = x + (size_t)b * SEQ + (r - 1) * KK;
      float xv[KK];
      #pragma unroll
      for (int k = 0; k < KK; ++k) xv[k] = xp[k];
      #pragma unroll
      for (int f = 0; f < DD; ++f) {
        float acc = conv_b[f];
        #pragma unroll
        for (int k = 0; k < KK; ++k) acc += xv[k] * conv_w[f * KK + k];
        h[f] = acc;
      }
    }
  }

  const float qs = 1.4426950408889634f * 0.70710678118654752f; // log2e / sqrt(2)

  for (int l = 0; l < NL; ++l) {
    const unsigned* wq16 = wpk + l * 384;
    const unsigned* wo16 = wpk + 3072 + l * 128;
    const unsigned* w116 = wpk + 4096 + l * 128;
    const unsigned* w216 = wpk + 5120 + l * 128;
    const float* bq  = bqkv + l * (3 * DD);
    const float* bol = bo   + l * DD;
    const float* b1l = b1   + l * FFD;
    const float* b2l = b2   + l * DD;
    const float* g1  = ln1_g + l * DD;  const float* be1 = ln1_b + l * DD;
    const float* g2  = ln2_g + l * DD;  const float* be2 = ln2_b + l * DD;

    __syncthreads();   // prior t-loop reads of s_kv complete

    h2 q2[NH];
    if (act) {
      h2 hv[8];
      #pragma unroll
      for (int i = 0; i < 8; ++i) hv[i] = pk_h2(h[2*i], h[2*i+1]);

      // q (pre-scaled fp16 pairs)
      #pragma unroll
      for (int hh = 0; hh < NH; ++hh) {
        const float a0 = dot16(hv, &wq16[(2*hh    ) * 8], bq[2*hh]);
        const float a1 = dot16(hv, &wq16[(2*hh + 1) * 8], bq[2*hh+1]);
        q2[hh] = pk_h2(a0 * qs, a1 * qs);
      }
      // k (fp16 pairs) and v (fp32, component-grouped) -> LDS row
      unsigned kdw[8];
      float    vx[8], vy[8];
      #pragma unroll
      for (int hh = 0; hh < NH; ++hh) {
        const int e0 = DD + 2 * hh;
        const float a0 = dot16(hv, &wq16[(e0    ) * 8], bq[e0]);
        const float a1 = dot16(hv, &wq16[(e0 + 1) * 8], bq[e0 + 1]);
        kdw[hh] = pk_u(a0, a1);
      }
      #pragma unroll
      for (int hh = 0; hh < NH; ++hh) {
        const int e0 = 2 * DD + 2 * hh;
        vx[hh] = dot16(hv, &wq16[(e0    ) * 8], bq[e0]);
        vy[hh] = dot16(hv, &wq16[(e0 + 1) * 8], bq[e0 + 1]);
      }
      unsigned* dst = &s_kv[j][r * ROWDW];
      ((uint4*)dst)[0] = make_uint4(kdw[0], kdw[1], kdw[2], kdw[3]);
      ((uint4*)dst)[1] = make_uint4(kdw[4], kdw[5], kdw[6], kdw[7]);
      float* fx = (float*)(dst + 8);
      ((float4*)fx)[0] = make_float4(vx[0], vx[1], vx[2], vx[3]);
      ((float4*)fx)[1] = make_float4(vx[4], vx[5], vx[6], vx[7]);
      float* fy = (float*)(dst + 16);
      ((float4*)fy)[0] = make_float4(vy[0], vy[1], vy[2], vy[3]);
      ((float4*)fy)[1] = make_float4(vy[4], vy[5], vy[6], vy[7]);
    }
    __syncthreads();   // kv visible block-wide

    if (act) {
      // ---- attention: wave-uniform b128 broadcast reads; packed f32 updates ----
      f2 lsum2[4], ctxX[4], ctxY[4];
      #pragma unroll
      for (int i = 0; i < 4; ++i) {
        lsum2[i].x = 0.f; lsum2[i].y = 0.f;
        ctxX[i].x = 0.f;  ctxX[i].y = 0.f;
        ctxY[i].x = 0.f;  ctxY[i].y = 0.f;
      }

      const unsigned* kv0 = &s_kv[j][0];
      #pragma unroll 2
      for (int t = 0; t < SS; ++t) {
        const unsigned* rp = kv0 + t * ROWDW;
        const uint4  ka  = ((const uint4*)rp)[0];
        const uint4  kb  = ((const uint4*)rp)[1];
        const float4 vxa = ((const float4*)(rp + 8))[0];
        const float4 vxb = ((const float4*)(rp + 8))[1];
        const float4 vya = ((const float4*)(rp + 16))[0];
        const float4 vyb = ((const float4*)(rp + 16))[1];

        const unsigned kd[8] = {ka.x, ka.y, ka.z, ka.w, kb.x, kb.y, kb.z, kb.w};
        f2 vx2[4], vy2[4];
        vx2[0].x = vxa.x; vx2[0].y = vxa.y;  vx2[1].x = vxa.z; vx2[1].y = vxa.w;
        vx2[2].x = vxb.x; vx2[2].y = vxb.y;  vx2[3].x = vxb.z; vx2[3].y = vxb.w;
        vy2[0].x = vya.x; vy2[0].y = vya.y;  vy2[1].x = vya.z; vy2[1].y = vya.w;
        vy2[2].x = vyb.x; vy2[2].y = vyb.y;  vy2[3].x = vyb.z; vy2[3].y = vyb.w;

        #pragma unroll
        for (int i = 0; i < 4; ++i) {
          const float s0 = fdot2(q2[2*i],     as_h2(kd[2*i]),     0.f);
          const float s1 = fdot2(q2[2*i + 1], as_h2(kd[2*i + 1]), 0.f);
          f2 p;
          p.x = exp2_fast(s0);
          p.y = exp2_fast(s1);
          pk_add(lsum2[i], p);          // v_pk_add_f32
          pk_fma(ctxX[i], vx2[i], p);   // v_pk_fma_f32
          pk_fma(ctxY[i], vy2[i], p);   // v_pk_fma_f32
        }
      }

      float cx[DD];
      #pragma unroll
      for (int i = 0; i < 4; ++i) {
        const float inv0 = rcp_fast(lsum2[i].x);
        const float inv1 = rcp_fast(lsum2[i].y);
        cx[2 * (2*i)]         = ctxX[i].x * inv0;
        cx[2 * (2*i) + 1]     = ctxY[i].x * inv0;
        cx[2 * (2*i + 1)]     = ctxX[i].y * inv1;
        cx[2 * (2*i + 1) + 1] = ctxY[i].y * inv1;
      }

      // ---- Wo + residual + LN1 ----
      h2 cv[8];
      #pragma unroll
      for (int i = 0; i < 8; ++i) cv[i] = pk_h2(cx[2*i], cx[2*i+1]);
      #pragma unroll
      for (int od = 0; od < DD; ++od)
        h[od] += dot16(cv, &wo16[od * 8], bol[od]);
      lnorm16(h, g1, be1);

      // ---- FF + residual + LN2 ----
      h2 hv2[8];
      #pragma unroll
      for (int i = 0; i < 8; ++i) hv2[i] = pk_h2(h[2*i], h[2*i+1]);
      float fv[FFD];
      #pragma unroll
      for (int f = 0; f < FFD; ++f)
        fv[f] = fmaxf(dot16(hv2, &w116[f * 8], b1l[f]), 0.f);
      h2 fv2[8];
      #pragma unroll
      for (int i = 0; i < 8; ++i) fv2[i] = pk_h2(fv[2*i], fv[2*i+1]);
      #pragma unroll
      for (int od = 0; od < DD; ++od)
        h[od] += dot16(fv2, &w216[od * 8], b2l[od]);
      lnorm16(h, g2, be2);
    }
  }

  // ---- final LN (cls rows) + head ----
  __syncthreads();
  if (act && r == 0) {
    lnorm16(h, lnf_g, lnf_b);
    #pragma unroll
    for (int d = 0; d < DD; ++d) s_cls[j][d] = h[d];
  }
  __syncthreads();
  if (tid < NBATCH * NP) {
    const int jj = tid / NP;
    const int oo = tid - jj * NP;
    if (blockIdx.x * NBATCH + jj < B) {
      float acc = end_b[oo];
      #pragma unroll
      for (int d = 0; d < DD; ++d) acc += s_cls[jj][d] * end_w[oo * DD + d];
      s_lat[jj][oo] = acc * head_w[oo];
    }
  }
  __syncthreads();
  if (tid < NBATCH) {
    const int bb = blockIdx.x * NBATCH + tid;
    if (bb < B) {
      float acc = head_b[0];
      for (int o = 0; o < NP; ++o) acc += s_lat[tid][o];
      out[bb] = rcp_fast(1.f + exp2_fast(-acc * 1.4426950408889634f));
    }
  }
}

// ---------------- fallback (no ws needed): f32 weights, LDS kv ----------------
#define FB_NBATCH 3
#define FB_NT 320
#define KROW 8
#define VROW 8
#define KREG (SS * KROW + 4)
#define VREG (SS * VROW + 2)

__global__ __launch_bounds__(FB_NT)
void transformer_fwd_lds(const float* __restrict__ x,
                         const float* __restrict__ conv_w,  const float* __restrict__ conv_b,
                         const float* __restrict__ cls_emb,
                         const float* __restrict__ Wqkv,    const float* __restrict__ bqkv,
                         const float* __restrict__ Wo,      const float* __restrict__ bo,
                         const float* __restrict__ W1,      const float* __restrict__ b1,
                         const float* __restrict__ W2,      const float* __restrict__ b2,
                         const float* __restrict__ ln1_g,   const float* __restrict__ ln1_b,
                         const float* __restrict__ ln2_g,   const float* __restrict__ ln2_b,
                         const float* __restrict__ lnf_g,   const float* __restrict__ lnf_b,
                         const float* __restrict__ end_w,   const float* __restrict__ end_b,
                         const float* __restrict__ head_w,  const float* __restrict__ head_b,
                         float* __restrict__ out, int B)
{
  __shared__ h2    s_K[FB_NBATCH][KREG];
  __shared__ f2    s_V[FB_NBATCH][VREG];
  __shared__ float s_cls[FB_NBATCH][DD];
  __shared__ float s_lat[FB_NBATCH][NP];

  const int tid = threadIdx.x;
  const int j   = tid / SS;
  const int r   = tid - j * SS;
  const int b   = blockIdx.x * FB_NBATCH + j;
  const bool act = (tid < FB_NBATCH * SS) && (b < B);

  float h[DD];
  if (act) {
    if (r == 0) {
      #pragma unroll
      for (int d = 0; d < DD; ++d) h[d] = cls_emb[d];
    } else {
      const float* xp = x + (size_t)b * SEQ + (r - 1) * KK;
      float xv[KK];
      #pragma unroll
      for (int k = 0; k < KK; ++k) xv[k] = xp[k];
      #pragma unroll
      for (int f = 0; f < DD; ++f) {
        float acc = conv_b[f];
        #pragma unroll
        for (int k = 0; k < KK; ++k) acc += xv[k] * conv_w[f * KK + k];
        h[f] = acc;
      }
    }
  }

  const float qs = 1.4426950408889634f * 0.70710678118654752f;

  for (int l = 0; l < NL; ++l) {
    const float* wq  = Wqkv + l * (3 * DD * DD);
    const float* bq  = bqkv + l * (3 * DD);
    const float* wo  = Wo   + l * (DD * DD);
    const float* bol = bo   + l * DD;
    const float* w1  = W1   + l * (FFD * DD);
    const float* b1l = b1   + l * FFD;
    const float* w2  = W2   + l * (DD * FFD);
    const float* b2l = b2   + l * DD;
    const float* g1  = ln1_g + l * DD;  const float* be1 = ln1_b + l * DD;
    const float* g2  = ln2_g + l * DD;  const float* be2 = ln2_b + l * DD;

    __syncthreads();

    h2 q2[NH];
    if (act) {
      #pragma unroll
      for (int hh = 0; hh < NH; ++hh) {
        const int e0 = 2 * hh;
        float a0 = bq[e0], a1 = bq[e0 + 1];
        #pragma unroll
        for (int d = 0; d < DD; ++d) {
          a0 += h[d] * wq[e0 * DD + d];
          a1 += h[d] * wq[(e0 + 1) * DD + d];
        }
        q2[hh] = pk_h2(a0 * qs, a1 * qs);
      }
      h2* kw = &s_K[j][r * KROW];
      #pragma unroll
      for (int hh = 0; hh < NH; ++hh) {
        const int e0 = DD + 2 * hh;
        float a0 = bq[e0], a1 = bq[e0 + 1];
        #pragma unroll
        for (int d = 0; d < DD; ++d) {
          a0 += h[d] * wq[e0 * DD + d];
          a1 += h[d] * wq[(e0 + 1) * DD + d];
        }
        kw[hh] = pk_h2(a0, a1);
      }
      f2* vw = &s_V[j][r * VROW];
      #pragma unroll
      for (int hh = 0; hh < NH; ++hh) {
        const int e0 = 2 * DD + 2 * hh;
        float a0 = bq[e0], a1 = bq[e0 + 1];
        #pragma unroll
        for (int d = 0; d < DD; ++d) {
          a0 += h[d] * wq[e0 * DD + d];
          a1 += h[d] * wq[(e0 + 1) * DD + d];
        }
        f2 vv; vv.x = a0; vv.y = a1;
        vw[hh] = vv;
      }
    }
    __syncthreads();

    if (act) {
      float lsum[NH];
      f2 ctx[NH];
      #pragma unroll
      for (int hh = 0; hh < NH; ++hh) { lsum[hh] = 0.f; ctx[hh].x = 0.f; ctx[hh].y = 0.f; }
      const h2* kp0 = &s_K[j][0];
      const f2* vp0 = &s_V[j][0];
      for (int t = 0; t < SS; ++t) {
        const h2* kp = kp0 + t * KROW;
        const f2* vp = vp0 + t * VROW;
        #pragma unroll
        for (int hh = 0; hh < NH; ++hh) {
          const float p = exp2_fast(fdot2(q2[hh], kp[hh], 0.0f));
          lsum[hh] += p;
          ctx[hh]  += vp[hh] * p;
        }
      }
      float cx[DD];
      #pragma unroll
      for (int hh = 0; hh < NH; ++hh) {
        const float inv = rcp_fast(lsum[hh]);
        cx[2 * hh]     = ctx[hh].x * inv;
        cx[2 * hh + 1] = ctx[hh].y * inv;
      }
      #pragma unroll
      for (int od = 0; od < DD; ++od) {
        float acc = bol[od];
        #pragma unroll
        for (int d = 0; d < DD; ++d) acc += cx[d] * wo[od * DD + d];
        h[od] += acc;
      }
      lnorm16(h, g1, be1);
      float fv[FFD];
      #pragma unroll
      for (int f = 0; f < FFD; ++f) {
        float acc = b1l[f];
        #pragma unroll
        for (int d = 0; d < DD; ++d) acc += h[d] * w1[f * DD + d];
        fv[f] = fmaxf(acc, 0.f);
      }
      #pragma unroll
      for (int od = 0; od < DD; ++od) {
        float acc = b2l[od];
        #pragma unroll
        for (int f = 0; f < FFD; ++f) acc += fv[f] * w2[od * FFD + f];
        h[od] += acc;
      }
      lnorm16(h, g2, be2);
    }
  }

  __syncthreads();
  if (act && r == 0) {
    lnorm16(h, lnf_g, lnf_b);
    #pragma unroll
    for (int d = 0; d < DD; ++d) s_cls[j][d] = h[d];
  }
  __syncthreads();
  if (tid < FB_NBATCH * NP) {
    const int jj = tid / NP;
    const int oo = tid - jj * NP;
    if (blockIdx.x * FB_NBATCH + jj < B) {
      float acc = end_b[oo];
      #pragma unroll
      for (int d = 0; d < DD; ++d) acc += s_cls[jj][d] * end_w[oo * DD + d];
      s_lat[jj][oo] = acc * head_w[oo];
    }
  }
  __syncthreads();
  if (tid < FB_NBATCH) {
    const int bb = blockIdx.x * FB_NBATCH + tid;
    if (bb < B) {
      float acc = head_b[0];
      for (int o = 0; o < NP; ++o) acc += s_lat[tid][o];
      out[bb] = rcp_fast(1.f + exp2_fast(-acc * 1.4426950408889634f));
    }
  }
}

extern "C" void kernel_launch(void* const* d_in, const int* in_sizes, int n_in,
                              void* d_out, int out_size, void* d_ws, size_t ws_size,
                              hipStream_t stream) {
  const float* x       = (const float*)d_in[0];
  const float* conv_w  = (const float*)d_in[1];
  const float* conv_b  = (const float*)d_in[2];
  const float* cls_emb = (const float*)d_in[3];
  const float* Wqkv    = (const float*)d_in[4];
  const float* bqkv    = (const float*)d_in[5];
  const float* Wo      = (const float*)d_in[6];
  const float* bo      = (const float*)d_in[7];
  const float* W1      = (const float*)d_in[8];
  const float* b1      = (const float*)d_in[9];
  const float* W2      = (const float*)d_in[10];
  const float* b2      = (const float*)d_in[11];
  const float* ln1_g   = (const float*)d_in[12];
  const float* ln1_b   = (const float*)d_in[13];
  const float* ln2_g   = (const float*)d_in[14];
  const float* ln2_b   = (const float*)d_in[15];
  const float* lnf_g   = (const float*)d_in[16];
  const float* lnf_b   = (const float*)d_in[17];
  const float* end_w   = (const float*)d_in[18];
  const float* end_b   = (const float*)d_in[19];
  const float* head_w  = (const float*)d_in[20];
  const float* head_b  = (const float*)d_in[21];
  float* out = (float*)d_out;

  const int B = in_sizes[0] / SEQ;   // 2048

  if (ws_size >= NWPAIR * sizeof(unsigned)) {
    unsigned* wpk = (unsigned*)d_ws;
    pack_weights<<<(NWPAIR + 255) / 256, 256, 0, stream>>>(Wqkv, Wo, W1, W2, wpk);
    const int nb = (B + NBATCH - 1) / NBATCH;   // 1024
    transformer_fwd_g<<<nb, NT, 0, stream>>>(
        x, conv_w, conv_b, cls_emb, bqkv, bo, b1, b2,
        ln1_g, ln1_b, ln2_g, ln2_b, lnf_g, lnf_b, end_w, end_b, head_w, head_b,
        out, wpk, B);
  } else {
    const int nb = (B + FB_NBATCH - 1) / FB_NBATCH;
    transformer_fwd_lds<<<nb, FB_NT, 0, stream>>>(
        x, conv_w, conv_b, cls_emb, Wqkv, bqkv, Wo, bo, W1, b1, W2, b2,
        ln1_g, ln1_b, ln2_g, ln2_b, lnf_g, lnf_b, end_w, end_b, head_w, head_b,
        out, B);
  }
}